// Round 13
// baseline (146.086 us; speedup 1.0000x reference)
//
#include <hip/hip_runtime.h>
#include <math.h>

// Problem constants
#define TN 4096        // sequence length N
#define DM 512         // model dim D = H*DH
#define NH 8           // heads
#define DHD 64         // head dim
#define MEM 4          // memory slots M
#define WINR 512       // window radius
#define JTOT (TN + MEM)   // 4100 total keys
#define JPAD 4168      // padded key rows so tile over-reads stay in-bounds
#define QK_SCALE 10.0f

typedef __attribute__((ext_vector_type(8))) short bf16x8;   // 8 bf16 = 4 VGPRs (MFMA A/B frag)
typedef __attribute__((ext_vector_type(4))) float f32x4;    // MFMA C/D frag

// fp32 -> bf16 round-to-nearest-even
__device__ __forceinline__ unsigned short f2bf(float f) {
    unsigned u = __float_as_uint(f);
    u = (u + 0x7FFFu + ((u >> 16) & 1u)) >> 16;
    return (unsigned short)u;
}

// async global->LDS, 16B per lane (wave writes base + lane*16, linear).
__device__ __forceinline__ void gl_lds16(const unsigned short* g, unsigned short* l) {
    __builtin_amdgcn_global_load_lds(
        (const __attribute__((address_space(1))) unsigned int*)g,
        (__attribute__((address_space(3))) unsigned int*)l, 16, 0, 0);
}

// ---------------------------------------------------------------------------
// Sectioned prep kernel (unchanged from round 12).
// ---------------------------------------------------------------------------
__global__ __launch_bounds__(256)
void prep(const float* __restrict__ X, unsigned short* __restrict__ Xb,
          const float* __restrict__ W0, const float* __restrict__ W1,
          const float* __restrict__ W2, const float* __restrict__ W3,
          const float* __restrict__ W4, unsigned short* __restrict__ T,
          const float* __restrict__ freqs, float2* __restrict__ tab,
          const float* __restrict__ mem_k, const float* __restrict__ mem_v,
          unsigned short* __restrict__ k_b, unsigned short* __restrict__ v_b)
{
    const int b = blockIdx.x;
    const int t = threadIdx.x;

    if (b < 2048) {                      // ---- cast X (full matrix)
        int idx = b * 256 + t;
        float4 v = *(const float4*)&X[(size_t)idx * 4];
        *(ushort4*)&Xb[(size_t)idx * 4] =
            make_ushort4(f2bf(v.x), f2bf(v.y), f2bf(v.z), f2bf(v.w));
    } else if (b < 2368) {               // ---- weight transpose+cast
        __shared__ unsigned short Ts[64][68];
        int bi = b - 2048;
        int sel = bi >> 6, tile = bi & 63;
        const float* __restrict__ W =
            (sel == 0) ? W0 : (sel == 1) ? W1 : (sel == 2) ? W2 : (sel == 3) ? W3 : W4;
        unsigned short* __restrict__ Wt = T + (size_t)sel * DM * DM;
        int r0 = (tile >> 3) * 64, c0 = (tile & 7) * 64;
        #pragma unroll
        for (int p = 0; p < 4; ++p) {
            int i  = p * 16 + (t >> 4);
            int j4 = (t & 15) * 4;
            float4 v = *(const float4*)&W[(size_t)(r0 + i) * DM + c0 + j4];
            Ts[i][j4 + 0] = f2bf(v.x); Ts[i][j4 + 1] = f2bf(v.y);
            Ts[i][j4 + 2] = f2bf(v.z); Ts[i][j4 + 3] = f2bf(v.w);
        }
        __syncthreads();
        #pragma unroll
        for (int p = 0; p < 4; ++p) {
            int oc  = p * 16 + (t >> 4);
            int or4 = (t & 15) * 4;
            *(ushort4*)&Wt[(size_t)(c0 + oc) * DM + r0 + or4] =
                make_ushort4(Ts[or4 + 0][oc], Ts[or4 + 1][oc],
                             Ts[or4 + 2][oc], Ts[or4 + 3][oc]);
        }
    } else if (b < 2432) {               // ---- rope cos/sin table
        int tid = (b - 2368) * 256 + t;
        #pragma unroll
        for (int e = 0; e < 16; ++e) {
            int id = e * 16384 + tid;
            float f = freqs[id];
            float sn, cs;
            sincosf(f, &sn, &cs);
            tab[id] = make_float2(cs, sn);
        }
    } else {                             // ---- memory KV rows
        int gw   = (b - 2432) * 4 + (t >> 6);
        int lane = t & 63;
        int h = gw >> 2, m = gw & 3;
        float kv = mem_k[(size_t)(h * MEM + m) * DHD + lane];
        float s = kv * kv;
        #pragma unroll
        for (int off = 1; off < 64; off <<= 1) s += __shfl_xor(s, off);
        kv = kv / fmaxf(sqrtf(s), 1e-12f);
        k_b[((size_t)h * JPAD + m) * 64 + lane] = f2bf(kv);
        v_b[((size_t)h * JPAD + m) * 64 + lane] =
            f2bf(mem_v[(size_t)(h * MEM + m) * DHD + lane]);
    }
}

// ---------------------------------------------------------------------------
// bf16 MFMA GEMM for Q/K/V/G projections (unchanged from round 12).
// ---------------------------------------------------------------------------
__global__ __launch_bounds__(256)
void gemm_qkvg_mfma(const unsigned short* __restrict__ Xb,
                    const unsigned short* __restrict__ Wt,
                    const float2* __restrict__ tab,
                    const float* __restrict__ bg,
                    unsigned short* __restrict__ q_b,
                    unsigned short* __restrict__ k_b,
                    unsigned short* __restrict__ v_b,
                    float* __restrict__ graw)
{
    __shared__ __align__(16) unsigned short As[128][32];
    __shared__ __align__(16) unsigned short Bs[128][32];
    const int sel = blockIdx.z;
    const unsigned short* __restrict__ Wsel = Wt + (size_t)sel * DM * DM;
    const int row0 = blockIdx.x * 128;
    const int col0 = blockIdx.y * 128;
    const int t = threadIdx.x;
    const int w = t >> 6, l = t & 63;
    const int wm = w >> 1, wn = w & 1;
    const int l15 = l & 15, lh = l >> 4;
    const int wb = t & 192;

    f32x4 acc[4][4];
    #pragma unroll
    for (int mi = 0; mi < 4; ++mi)
        #pragma unroll
        for (int ni = 0; ni < 4; ++ni)
            acc[mi][ni] = (f32x4){0.f, 0.f, 0.f, 0.f};

    for (int k0 = 0; k0 < DM; k0 += 32) {
        __syncthreads();
        #pragma unroll
        for (int cc = 0; cc < 2; ++cc) {
            int c = t + cc * 256;
            int row = c >> 2, k8 = c & 3;
            gl_lds16(&Xb[(size_t)(row0 + row) * DM + k0 + k8 * 8],
                     &As[0][0] + (size_t)(wb + cc * 256) * 8);
            gl_lds16(&Wsel[(size_t)(col0 + row) * DM + k0 + k8 * 8],
                     &Bs[0][0] + (size_t)(wb + cc * 256) * 8);
        }
        __syncthreads();

        bf16x8 af[4], bfr[4];
        #pragma unroll
        for (int mi = 0; mi < 4; ++mi)
            af[mi] = *(const bf16x8*)&As[wm * 64 + mi * 16 + l15][lh * 8];
        #pragma unroll
        for (int ni = 0; ni < 4; ++ni)
            bfr[ni] = *(const bf16x8*)&Bs[wn * 64 + ni * 16 + l15][lh * 8];
        #pragma unroll
        for (int mi = 0; mi < 4; ++mi)
            #pragma unroll
            for (int ni = 0; ni < 4; ++ni)
                acc[mi][ni] = __builtin_amdgcn_mfma_f32_16x16x32_bf16(
                    af[mi], bfr[ni], acc[mi][ni], 0, 0, 0);
    }

    if (sel <= 1) {
        const int h = (col0 + wn * 64) >> 6;
        #pragma unroll
        for (int mi = 0; mi < 4; ++mi) {
            #pragma unroll
            for (int r = 0; r < 4; ++r) {
                float v0 = acc[mi][0][r], v1 = acc[mi][1][r];
                float v2 = acc[mi][2][r], v3 = acc[mi][3][r];
                float ss = v0 * v0 + v1 * v1 + v2 * v2 + v3 * v3;
                ss += __shfl_xor(ss, 1); ss += __shfl_xor(ss, 2);
                ss += __shfl_xor(ss, 4); ss += __shfl_xor(ss, 8);
                float inv = 1.0f / fmaxf(sqrtf(ss), 1e-12f);
                v0 *= inv; v1 *= inv; v2 *= inv; v3 *= inv;
                int n = row0 + wm * 64 + mi * 16 + lh * 4 + r;
                float2 t0 = tab[n * 64 + l15];
                float2 t1 = tab[n * 64 + 16 + l15];
                float o0 = v0 * t0.x - v2 * t0.y;
                float o1 = v1 * t1.x - v3 * t1.y;
                float o2 = v2 * t0.x + v0 * t0.y;
                float o3 = v3 * t1.x + v1 * t1.y;
                unsigned short* dst = (sel == 0)
                    ? &q_b[((size_t)h * TN + n) * 64]
                    : &k_b[((size_t)h * JPAD + MEM + n) * 64];
                dst[l15]      = f2bf(o0);
                dst[16 + l15] = f2bf(o1);
                dst[32 + l15] = f2bf(o2);
                dst[48 + l15] = f2bf(o3);
            }
        }
    } else if (sel == 2) {
        const int h = (col0 + wn * 64) >> 6;
        #pragma unroll
        for (int mi = 0; mi < 4; ++mi)
            #pragma unroll
            for (int ni = 0; ni < 4; ++ni) {
                int d = ni * 16 + l15;
                #pragma unroll
                for (int r = 0; r < 4; ++r) {
                    int grow = row0 + wm * 64 + mi * 16 + lh * 4 + r;
                    v_b[((size_t)h * JPAD + MEM + grow) * 64 + d] = f2bf(acc[mi][ni][r]);
                }
            }
    } else {
        #pragma unroll
        for (int mi = 0; mi < 4; ++mi)
            #pragma unroll
            for (int ni = 0; ni < 4; ++ni) {
                int gcol = col0 + wn * 64 + ni * 16 + l15;
                float bgv = bg[gcol];
                #pragma unroll
                for (int r = 0; r < 4; ++r) {
                    int grow = row0 + wm * 64 + mi * 16 + lh * 4 + r;
                    float g = acc[mi][ni][r] + bgv;
                    graw[(size_t)grow * DM + gcol] = 1.0f / (1.0f + __expf(-g));
                }
            }
    }
}

// ---------------------------------------------------------------------------
// bf16 MFMA GEMM: d_out = attnb @ Wo (unchanged from round 12).
// ---------------------------------------------------------------------------
__global__ __launch_bounds__(256)
void gemm_out_mfma(const unsigned short* __restrict__ Ab,
                   const unsigned short* __restrict__ Wot,
                   float* __restrict__ C)
{
    __shared__ __align__(16) unsigned short As[128][32];
    __shared__ __align__(16) unsigned short Bs[128][32];
    const int row0 = blockIdx.x * 128;
    const int col0 = blockIdx.y * 128;
    const int t = threadIdx.x;
    const int w = t >> 6, l = t & 63;
    const int wm = w >> 1, wn = w & 1;
    const int wb = t & 192;

    f32x4 acc[4][4];
    #pragma unroll
    for (int mi = 0; mi < 4; ++mi)
        #pragma unroll
        for (int ni = 0; ni < 4; ++ni)
            acc[mi][ni] = (f32x4){0.f, 0.f, 0.f, 0.f};

    for (int k0 = 0; k0 < DM; k0 += 32) {
        __syncthreads();
        #pragma unroll
        for (int cc = 0; cc < 2; ++cc) {
            int c = t + cc * 256;
            int row = c >> 2, k8 = c & 3;
            gl_lds16(&Ab[(size_t)(row0 + row) * DM + k0 + k8 * 8],
                     &As[0][0] + (size_t)(wb + cc * 256) * 8);
            gl_lds16(&Wot[(size_t)(col0 + row) * DM + k0 + k8 * 8],
                     &Bs[0][0] + (size_t)(wb + cc * 256) * 8);
        }
        __syncthreads();

        bf16x8 af[4], bfr[4];
        #pragma unroll
        for (int mi = 0; mi < 4; ++mi)
            af[mi] = *(const bf16x8*)&As[wm * 64 + mi * 16 + (l & 15)][(l >> 4) * 8];
        #pragma unroll
        for (int ni = 0; ni < 4; ++ni)
            bfr[ni] = *(const bf16x8*)&Bs[wn * 64 + ni * 16 + (l & 15)][(l >> 4) * 8];
        #pragma unroll
        for (int mi = 0; mi < 4; ++mi)
            #pragma unroll
            for (int ni = 0; ni < 4; ++ni)
                acc[mi][ni] = __builtin_amdgcn_mfma_f32_16x16x32_bf16(
                    af[mi], bfr[ni], acc[mi][ni], 0, 0, 0);
    }

    #pragma unroll
    for (int mi = 0; mi < 4; ++mi)
        #pragma unroll
        for (int ni = 0; ni < 4; ++ni) {
            int gcol = col0 + wn * 64 + ni * 16 + (l & 15);
            #pragma unroll
            for (int r = 0; r < 4; ++r) {
                int grow = row0 + wm * 64 + mi * 16 + (l >> 4) * 4 + r;
                C[(size_t)grow * DM + gcol] = acc[mi][ni][r];
            }
        }
}

// ---------------------------------------------------------------------------
// MFMA flash attention, 768 threads = 3 independent j-groups of 4 waves.
// Changes vs r12: (a) Q per-wave in REGISTERS (each wave's A-frag rows are its
// own -> no Qs tile, no Q staging); (b) tile stride 72->68 (136B rows: b128
// quarter-wave reads 2-way banked = free); (c) 3-way j-split. LDS = 9 tiles
// x 8.7KB = 78.3KB -> 2 blocks/CU = 24 waves/CU (was 16). Serial j-chain per
// group 9 -> 6 tiles. Fixed-max softmax + mask hoist + T14 + setprio kept.
// ---------------------------------------------------------------------------
#define TILE68 (64 * 68)
__global__ __launch_bounds__(768)
void attn_mfma(const unsigned short* __restrict__ qb,
               const unsigned short* __restrict__ kb,
               const unsigned short* __restrict__ vb,
               const float* __restrict__ gate,
               unsigned short* __restrict__ attnb)
{
    __shared__ __align__(16) unsigned short smem[TILE68 * 9];
    #define KS(g) (smem + TILE68 * (g))
    #define VT(g) (smem + TILE68 * (3 + (g)))
    #define PS(g) (smem + TILE68 * (6 + (g)))

    // XCD swizzle: blocks of one head land on one XCD (K/V L2 reuse)
    const int sw   = (blockIdx.x & 7) * 64 + (blockIdx.x >> 3);
    const int head = sw >> 6;
    const int n0   = (sw & 63) * 64;
    const int t   = threadIdx.x;
    const int g   = t >> 8;          // j-group 0/1/2
    const int tig = t & 255;         // thread-in-group
    const int wid = (tig >> 6);      // q-band within group (0..3)
    const int l   = t & 63;
    const int l15 = l & 15, lh = l >> 4;

    // Q per-wave in registers: this wave's A-frags for both k-halves
    bf16x8 qr[2];
    #pragma unroll
    for (int s = 0; s < 2; ++s)
        qr[s] = *(const bf16x8*)&qb[((size_t)(head * TN + n0 + wid * 16 + l15)) * 64
                                    + s * 32 + lh * 8];

    f32x4 oacc[4];
    #pragma unroll
    for (int dt = 0; dt < 4; ++dt) oacc[dt] = (f32x4){0.f, 0.f, 0.f, 0.f};
    float lpart[4] = {0.f, 0.f, 0.f, 0.f};

    const int p_base = MEM + n0;
    const int kstart = max(0, p_base - WINR);
    const int kend   = min(JTOT, p_base + 63 + WINR + 1);
    const int ntiles = (kend - kstart + 63) >> 6;     // >= 10 always
    const int niter  = (ntiles + 2) / 3;

    // staging addresses (within group: 256 threads stage one 64-tile)
    const int srow = tig >> 3, sc8 = (tig & 7) * 8;
    const int srow2 = (tig + 256) >> 3, sc82 = ((tig + 256) & 7) * 8;
    const int vj = tig & 63, vd0 = (tig >> 6) * 8;
    const int vj2 = (tig + 256) & 63, vd02 = ((tig + 256) >> 6) * 8;
    bf16x8 kr0, kr1, vr0, vr1;

    int tj = g;   // group g handles tiles g, g+3, g+6, ...
    {
        int j0 = kstart + tj * 64;
        kr0 = *(const bf16x8*)&kb[((size_t)head * JPAD + j0 + srow) * 64 + sc8];
        kr1 = *(const bf16x8*)&kb[((size_t)head * JPAD + j0 + srow2) * 64 + sc82];
        vr0 = *(const bf16x8*)&vb[((size_t)head * JPAD + j0 + vj) * 64 + vd0];
        vr1 = *(const bf16x8*)&vb[((size_t)head * JPAD + j0 + vj2) * 64 + vd02];
    }

    for (int it = 0; it < niter; ++it) {
        bool valid = (tj < ntiles);
        __syncthreads();   // prior iteration's LDS consumers done
        if (valid) {
            *(bf16x8*)&KS(g)[srow * 68 + sc8]   = kr0;
            *(bf16x8*)&KS(g)[srow2 * 68 + sc82] = kr1;
            #pragma unroll
            for (int i = 0; i < 8; ++i) VT(g)[(vd0 + i) * 68 + vj]   = (unsigned short)vr0[i];
            #pragma unroll
            for (int i = 0; i < 8; ++i) VT(g)[(vd02 + i) * 68 + vj2] = (unsigned short)vr1[i];
        }
        __syncthreads();

        if (valid) {
            int j0 = kstart + tj * 64;
            if (tj + 3 < ntiles) {
                int jn = kstart + (tj + 3) * 64;
                kr0 = *(const bf16x8*)&kb[((size_t)head * JPAD + jn + srow) * 64 + sc8];
                kr1 = *(const bf16x8*)&kb[((size_t)head * JPAD + jn + srow2) * 64 + sc82];
                vr0 = *(const bf16x8*)&vb[((size_t)head * JPAD + jn + vj) * 64 + vd0];
                vr1 = *(const bf16x8*)&vb[((size_t)head * JPAD + jn + vj2) * 64 + vd02];
            }

            // S band = Q[band] @ K^T
            f32x4 sacc[4];
            #pragma unroll
            for (int kt = 0; kt < 4; ++kt) sacc[kt] = (f32x4){0.f, 0.f, 0.f, 0.f};
            __builtin_amdgcn_s_setprio(1);
            #pragma unroll
            for (int s = 0; s < 2; ++s) {
                #pragma unroll
                for (int kt = 0; kt < 4; ++kt) {
                    bf16x8 b = *(const bf16x8*)&KS(g)[(kt * 16 + l15) * 68 + s * 32 + lh * 8];
                    sacc[kt] = __builtin_amdgcn_mfma_f32_16x16x32_bf16(qr[s], b, sacc[kt], 0, 0, 0);
                }
            }
            __builtin_amdgcn_s_setprio(0);

            // fixed-max softmax: P = exp(10*s - 10). Wave-uniform mask hoist.
            int qlo = p_base + wid * 16;
            bool fullok = ((qlo + 15 - j0) <= WINR) &&
                          ((qlo - (j0 + 63)) >= -WINR) &&
                          (j0 + 63 < JTOT);
            if (fullok) {
                #pragma unroll
                for (int r = 0; r < 4; ++r) {
                    #pragma unroll
                    for (int kt = 0; kt < 4; ++kt) {
                        float pe = __expf(sacc[kt][r] * QK_SCALE - 10.0f);
                        lpart[r] += pe;
                        PS(g)[(wid * 16 + lh * 4 + r) * 68 + kt * 16 + l15] = f2bf(pe);
                    }
                }
            } else {
                #pragma unroll
                for (int r = 0; r < 4; ++r) {
                    int pq = p_base + wid * 16 + lh * 4 + r;
                    #pragma unroll
                    for (int kt = 0; kt < 4; ++kt) {
                        int j = j0 + kt * 16 + l15;
                        int dist = pq - j;
                        bool ok = (dist <= WINR) && (dist >= -WINR) && (j < JTOT);
                        float pe = ok ? __expf(sacc[kt][r] * QK_SCALE - 10.0f) : 0.f;
                        lpart[r] += pe;
                        PS(g)[(wid * 16 + lh * 4 + r) * 68 + kt * 16 + l15] = f2bf(pe);
                    }
                }
            }

            // O += P @ V (Ps rows wave-own; lgkmcnt ordering suffices)
            __builtin_amdgcn_s_setprio(1);
            #pragma unroll
            for (int s = 0; s < 2; ++s) {
                bf16x8 a = *(const bf16x8*)&PS(g)[(wid * 16 + l15) * 68 + s * 32 + lh * 8];
                #pragma unroll
                for (int dt = 0; dt < 4; ++dt) {
                    bf16x8 b = *(const bf16x8*)&VT(g)[(dt * 16 + l15) * 68 + s * 32 + lh * 8];
                    oacc[dt] = __builtin_amdgcn_mfma_f32_16x16x32_bf16(a, b, oacc[dt], 0, 0, 0);
                }
            }
            __builtin_amdgcn_s_setprio(0);
        }
        tj += 3;
    }

    // ---- combine group partials (fbuf aliases smem; all tiles dead) ----
    float* fbuf = (float*)smem;   // groups 1,2: 2 x 256 x 21 floats = 43KB < 78.3KB
    __syncthreads();
    if (g >= 1) {
        int base = (g - 1) * 256 * 21 + tig * 21;
        #pragma unroll
        for (int dt = 0; dt < 4; ++dt)
            #pragma unroll
            for (int r = 0; r < 4; ++r)
                fbuf[base + dt * 4 + r] = oacc[dt][r];
        #pragma unroll
        for (int r = 0; r < 4; ++r) fbuf[base + 16 + r] = lpart[r];
    }
    __syncthreads();
    if (g == 0) {
        #pragma unroll
        for (int gg = 0; gg < 2; ++gg) {
            int base = gg * 256 * 21 + tig * 21;
            #pragma unroll
            for (int dt = 0; dt < 4; ++dt)
                #pragma unroll
                for (int r = 0; r < 4; ++r)
                    oacc[dt][r] += fbuf[base + dt * 4 + r];
            #pragma unroll
            for (int r = 0; r < 4; ++r) lpart[r] += fbuf[base + 16 + r];
        }

        // epilogue: row-sum reduce over l15 lanes, normalize, gate, store
        #pragma unroll
        for (int r = 0; r < 4; ++r) {
            float rs = lpart[r];
            rs += __shfl_xor(rs, 1); rs += __shfl_xor(rs, 2);
            rs += __shfl_xor(rs, 4); rs += __shfl_xor(rs, 8);
            float inv = 1.0f / rs;
            int n = n0 + wid * 16 + lh * 4 + r;
            #pragma unroll
            for (int dt = 0; dt < 4; ++dt) {
                int col = head * 64 + dt * 16 + l15;
                float gv = gate[(size_t)n * DM + col];
                attnb[(size_t)n * DM + col] = f2bf(oacc[dt][r] * inv * gv);
            }
        }
    }
}

// ---------------------------------------------------------------------------
extern "C" void kernel_launch(void* const* d_in, const int* in_sizes, int n_in,
                              void* d_out, int out_size, void* d_ws, size_t ws_size,
                              hipStream_t stream)
{
    const float* x     = (const float*)d_in[0];
    const float* Wq    = (const float*)d_in[1];
    const float* Wk    = (const float*)d_in[2];
    const float* Wv    = (const float*)d_in[3];
    const float* Wg    = (const float*)d_in[4];
    const float* bg    = (const float*)d_in[5];
    const float* Wo    = (const float*)d_in[6];
    const float* mem_k = (const float*)d_in[7];
    const float* mem_v = (const float*)d_in[8];
    const float* freqs = (const float*)d_in[9];

    // Workspace (~28.8 MB). attnb aliases Xb (Xb dead after gemm_qkvg_mfma).
    unsigned short* q_b = (unsigned short*)d_ws;               // [H][N][64] bf16
    unsigned short* k_b = q_b + (size_t)NH * TN * DHD;         // [H][JPAD][64] bf16
    unsigned short* v_b = k_b + (size_t)NH * JPAD * DHD;       // [H][JPAD][64] bf16
    unsigned short* Xb  = v_b + (size_t)NH * JPAD * DHD;       // [N][512] bf16
    unsigned short* attnb = Xb;                                // alias
    unsigned short* Wt  = Xb + (size_t)TN * DM;                // 5x[512][512] bf16
    float* graw = (float*)(Wt + (size_t)5 * DM * DM);          // [N][512] fp32 gate
    float2* tab = (float2*)(graw + (size_t)TN * DM);           // [4096][64] cos/sin

    // 0) prep: cast X, transpose weights, rope table, memory KV rows
    prep<<<dim3(2440), 256, 0, stream>>>(x, Xb, Wq, Wk, Wv, Wg, Wo, Wt,
                                         freqs, tab, mem_k, mem_v, k_b, v_b);

    // 1) Q/K/V/G projections (bf16 MFMA, global_load_lds) + fused epilogues
    gemm_qkvg_mfma<<<dim3(TN / 128, DM / 128, 4), 256, 0, stream>>>(
        Xb, Wt, tab, bg, q_b, k_b, v_b, graw);

    // 2) MFMA local-window attention (3 j-groups, Q-in-reg, fixed-max softmax)
    attn_mfma<<<dim3(512), 768, 0, stream>>>(q_b, k_b, v_b, graw, attnb);

    // 3) output projection (bf16 MFMA, global_load_lds)
    gemm_out_mfma<<<dim3(TN / 128, DM / 128), 256, 0, stream>>>(
        attnb, Wt + (size_t)4 * DM * DM, (float*)d_out);
}